// Round 1
// baseline (8226.532 us; speedup 1.0000x reference)
//
#include <hip/hip_runtime.h>
#include <math.h>

// Problem constants
#define Bv 2
#define Lv 1024
#define Dv 512
#define Hv 8
#define DH 64
#define Fv 2048
#define NBv 6
#define Vv 32000
#define Mv (Bv*Lv)          // 2048 rows
#define NEGINF -1e10f

// ---------------------------------------------------------------------------
// Embedding + sinusoidal positional encoding
// h[row][d] = emb[x[row]][d]*sqrt(512) + PE(l, d)
// grid: 2048 blocks (one per row), 256 threads
__global__ __launch_bounds__(256)
void embed_kernel(const int* __restrict__ xi, const float* __restrict__ emb,
                  float* __restrict__ h)
{
    const int row = blockIdx.x;
    const int l   = row & (Lv - 1);
    const int tok = xi[row];
    const int tid = threadIdx.x;
#pragma unroll
    for (int s = 0; s < 2; ++s) {
        const int d  = tid + s * 256;
        const int dd = d & 255;                       // i within half
        const float freq = powf(10000.f, (float)dd * (1.f / 256.f));
        const float arg  = (float)l / freq;
        const float pe   = (d < 256) ? sinf(arg) : cosf(arg);
        h[(size_t)row * Dv + d] = emb[(size_t)tok * Dv + d] * 22.62741699796952f + pe;
    }
}

// ---------------------------------------------------------------------------
// LayerNorm: one block per row, 256 threads, D=512 (2 elems/thread)
__global__ __launch_bounds__(256)
void ln_kernel(const float* __restrict__ X, const float* __restrict__ g,
               const float* __restrict__ bta, float* __restrict__ Y)
{
    const int row = blockIdx.x, tid = threadIdx.x;
    const float* xr = X + (size_t)row * Dv;
    const float x0 = xr[tid], x1 = xr[tid + 256];
    __shared__ float red[4];

    float s = x0 + x1;
#pragma unroll
    for (int off = 32; off; off >>= 1) s += __shfl_xor(s, off);
    if ((tid & 63) == 0) red[tid >> 6] = s;
    __syncthreads();
    const float mean = (red[0] + red[1] + red[2] + red[3]) * (1.f / Dv);
    __syncthreads();

    const float d0 = x0 - mean, d1 = x1 - mean;
    float v = d0 * d0 + d1 * d1;
#pragma unroll
    for (int off = 32; off; off >>= 1) v += __shfl_xor(v, off);
    if ((tid & 63) == 0) red[tid >> 6] = v;
    __syncthreads();
    const float var  = (red[0] + red[1] + red[2] + red[3]) * (1.f / Dv);
    const float rstd = rsqrtf(var + 1e-6f);

    Y[(size_t)row * Dv + tid]       = d0 * rstd * g[tid]       + bta[tid];
    Y[(size_t)row * Dv + tid + 256] = d1 * rstd * g[tid + 256] + bta[tid + 256];
}

// ---------------------------------------------------------------------------
// Tiled fp32 GEMM. A:[M,K] rm. BT=false: B:[K,N] rm. BT=true: B:[N,K] rm.
// C = A@B (+bias[n]) (+residual[m,n]) (relu?). All dims multiples of tiles.
// 256 threads, tile 64x64x16, 4x4 per thread.
template <bool BT>
__global__ __launch_bounds__(256)
void gemm_kernel(const float* __restrict__ A, const float* __restrict__ B,
                 float* __restrict__ C, int M, int N, int K,
                 const float* __restrict__ bias,
                 const float* __restrict__ residual, int relu)
{
    __shared__ float As[64][17];
    __shared__ float Bs[16][65];
    const int tid = threadIdx.x;
    const int tx = tid & 15, ty = tid >> 4;
    const int m0 = blockIdx.y * 64, n0 = blockIdx.x * 64;
    float acc[4][4] = {};

    const int ar = tid >> 2;            // A tile row 0..63
    const int ac = (tid & 3) * 4;       // A tile col {0,4,8,12}

    for (int k0 = 0; k0 < K; k0 += 16) {
        const float4 av = *(const float4*)(A + (size_t)(m0 + ar) * K + k0 + ac);
        As[ar][ac + 0] = av.x; As[ar][ac + 1] = av.y;
        As[ar][ac + 2] = av.z; As[ar][ac + 3] = av.w;
        if (!BT) {
            const int br = tid >> 4;          // k row 0..15
            const int bc = (tid & 15) * 4;    // n col
            const float4 bv = *(const float4*)(B + (size_t)(k0 + br) * N + n0 + bc);
            Bs[br][bc + 0] = bv.x; Bs[br][bc + 1] = bv.y;
            Bs[br][bc + 2] = bv.z; Bs[br][bc + 3] = bv.w;
        } else {
            const int br = tid >> 2;          // n row 0..63
            const int bc = (tid & 3) * 4;     // k col
            const float4 bv = *(const float4*)(B + (size_t)(n0 + br) * K + k0 + bc);
            Bs[bc + 0][br] = bv.x; Bs[bc + 1][br] = bv.y;
            Bs[bc + 2][br] = bv.z; Bs[bc + 3][br] = bv.w;
        }
        __syncthreads();
#pragma unroll
        for (int kk = 0; kk < 16; ++kk) {
            float a[4], bb[4];
#pragma unroll
            for (int i = 0; i < 4; ++i) a[i] = As[ty * 4 + i][kk];
#pragma unroll
            for (int j = 0; j < 4; ++j) bb[j] = Bs[kk][tx * 4 + j];
#pragma unroll
            for (int i = 0; i < 4; ++i)
#pragma unroll
                for (int j = 0; j < 4; ++j)
                    acc[i][j] += a[i] * bb[j];
        }
        __syncthreads();
    }

#pragma unroll
    for (int i = 0; i < 4; ++i) {
        const int m = m0 + ty * 4 + i;
#pragma unroll
        for (int j = 0; j < 4; ++j) {
            const int n = n0 + tx * 4 + j;
            float v = acc[i][j];
            if (bias)     v += bias[n];
            if (residual) v += residual[(size_t)m * N + n];
            if (relu)     v = fmaxf(v, 0.f);
            C[(size_t)m * N + n] = v;
        }
    }
}

// ---------------------------------------------------------------------------
// Attention: softmax(Q K^T / 8 (+causal)) V, heads as column slices of D.
// grid (L/4, H, B); block 256 = 4 waves; one wave per query row.
__global__ __launch_bounds__(256)
void attn_kernel(const float* __restrict__ Qp, const float* __restrict__ Kp,
                 const float* __restrict__ Vp, float* __restrict__ Op, int causal)
{
    __shared__ float ks[64][65];
    __shared__ float qs[4][64];
    __shared__ float sc[4][Lv];
    const int tid  = threadIdx.x;
    const int wave = tid >> 6, lane = tid & 63;
    const int hh = blockIdx.y, bb = blockIdx.z;
    const int q  = blockIdx.x * 4 + wave;
    const size_t headoff = (size_t)hh * DH;
    const size_t rowQ = ((size_t)bb * Lv + q) * Dv + headoff;

    qs[wave][lane] = Qp[rowQ + lane] * 0.125f;   // fold 1/sqrt(64)

    for (int t = 0; t < 16; ++t) {               // 16 key tiles of 64
        const int j0 = t * 64;
        __syncthreads();                          // protect ks reuse
#pragma unroll
        for (int s = 0; s < 16; ++s) {
            const int e = s * 256 + tid;
            const int j = e >> 6, d = e & 63;
            ks[j][d] = Kp[((size_t)bb * Lv + j0 + j) * Dv + headoff + d];
        }
        __syncthreads();
        const int j = j0 + lane;
        float sv;
        if (causal && j > q) {
            sv = NEGINF;                          // == s/8 + (-1e10) in fp32
        } else {
            sv = 0.f;
#pragma unroll
            for (int d = 0; d < 64; ++d) sv += qs[wave][d] * ks[lane][d];
        }
        sc[wave][j] = sv;
    }

    // wave-local softmax over 1024 scores
    float m = -3.4e38f;
#pragma unroll
    for (int t = 0; t < 16; ++t) m = fmaxf(m, sc[wave][t * 64 + lane]);
#pragma unroll
    for (int off = 32; off; off >>= 1) m = fmaxf(m, __shfl_xor(m, off));
    float sum = 0.f;
#pragma unroll
    for (int t = 0; t < 16; ++t) {
        const float p = expf(sc[wave][t * 64 + lane] - m);
        sc[wave][t * 64 + lane] = p;
        sum += p;
    }
#pragma unroll
    for (int off = 32; off; off >>= 1) sum += __shfl_xor(sum, off);
    const float inv = 1.f / sum;

    const int jmax = causal ? q : (Lv - 1);      // masked probs are exactly 0
    float o = 0.f;
    for (int j = 0; j <= jmax; ++j)
        o += sc[wave][j] * Vp[((size_t)bb * Lv + j) * Dv + headoff + lane];
    Op[rowQ + lane] = o * inv;
}

// ---------------------------------------------------------------------------
extern "C" void kernel_launch(void* const* d_in, const int* in_sizes, int n_in,
                              void* d_out, int out_size, void* d_ws, size_t ws_size,
                              hipStream_t stream)
{
    const int*   x    = (const int*)  d_in[0];
    const float* ctx  = (const float*)d_in[1];
    const float* emb  = (const float*)d_in[2];
    const float* wq_s = (const float*)d_in[3];
    const float* wk_s = (const float*)d_in[4];
    const float* wv_s = (const float*)d_in[5];
    const float* wo_s = (const float*)d_in[6];
    const float* wq_c = (const float*)d_in[7];
    const float* wk_c = (const float*)d_in[8];
    const float* wv_c = (const float*)d_in[9];
    const float* wo_c = (const float*)d_in[10];
    const float* w1   = (const float*)d_in[11];
    const float* b1   = (const float*)d_in[12];
    const float* w2   = (const float*)d_in[13];
    const float* b2   = (const float*)d_in[14];
    const float* ln1g = (const float*)d_in[15];
    const float* ln1b = (const float*)d_in[16];
    const float* ln2g = (const float*)d_in[17];
    const float* ln2b = (const float*)d_in[18];
    const float* ln3g = (const float*)d_in[19];
    const float* ln3b = (const float*)d_in[20];
    const float* lnfg = (const float*)d_in[21];
    const float* lnfb = (const float*)d_in[22];
    float* out = (float*)d_out;

    // workspace layout (floats): h | y | {q,k,v,ao} == ff(4M)
    float* ws = (float*)d_ws;
    const size_t SZ = (size_t)Mv * Dv;   // 1M floats
    float* h  = ws;
    float* y  = ws + SZ;
    float* qb = ws + 2 * SZ;
    float* kb = ws + 3 * SZ;
    float* vb = ws + 4 * SZ;
    float* ao = ws + 5 * SZ;
    float* ff = qb;                      // 4M floats spanning qb..ao

    const dim3 blk(256);
    const dim3 gAttn(Lv / 4, Hv, Bv);
    const dim3 gD(Dv / 64, Mv / 64);     // (8,32)
    const dim3 gF(Fv / 64, Mv / 64);     // (32,32)
    const dim3 gV(Vv / 64, Mv / 64);     // (500,32)

    embed_kernel<<<Mv, blk, 0, stream>>>(x, emb, h);

    for (int i = 0; i < NBv; ++i) {
        const size_t wOff = (size_t)i * Dv * Dv;
        // --- self attention ---
        ln_kernel<<<Mv, blk, 0, stream>>>(h, ln1g + i * Dv, ln1b + i * Dv, y);
        gemm_kernel<false><<<gD, blk, 0, stream>>>(y, wq_s + wOff, qb, Mv, Dv, Dv, nullptr, nullptr, 0);
        gemm_kernel<false><<<gD, blk, 0, stream>>>(y, wk_s + wOff, kb, Mv, Dv, Dv, nullptr, nullptr, 0);
        gemm_kernel<false><<<gD, blk, 0, stream>>>(y, wv_s + wOff, vb, Mv, Dv, Dv, nullptr, nullptr, 0);
        attn_kernel<<<gAttn, blk, 0, stream>>>(qb, kb, vb, ao, 1);
        gemm_kernel<false><<<gD, blk, 0, stream>>>(ao, wo_s + wOff, h, Mv, Dv, Dv, nullptr, h, 0);
        // --- cross attention ---
        ln_kernel<<<Mv, blk, 0, stream>>>(h, ln2g + i * Dv, ln2b + i * Dv, y);
        gemm_kernel<false><<<gD, blk, 0, stream>>>(y,   wq_c + wOff, qb, Mv, Dv, Dv, nullptr, nullptr, 0);
        gemm_kernel<false><<<gD, blk, 0, stream>>>(ctx, wk_c + wOff, kb, Mv, Dv, Dv, nullptr, nullptr, 0);
        gemm_kernel<false><<<gD, blk, 0, stream>>>(ctx, wv_c + wOff, vb, Mv, Dv, Dv, nullptr, nullptr, 0);
        attn_kernel<<<gAttn, blk, 0, stream>>>(qb, kb, vb, ao, 0);
        gemm_kernel<false><<<gD, blk, 0, stream>>>(ao, wo_c + wOff, h, Mv, Dv, Dv, nullptr, h, 0);
        // --- feed forward ---
        ln_kernel<<<Mv, blk, 0, stream>>>(h, ln3g + i * Dv, ln3b + i * Dv, y);
        gemm_kernel<false><<<gF, blk, 0, stream>>>(y, w1 + (size_t)i * Dv * Fv, ff,
                                                   Mv, Fv, Dv, b1 + (size_t)i * Fv, nullptr, 1);
        gemm_kernel<false><<<gD, blk, 0, stream>>>(ff, w2 + (size_t)i * Fv * Dv, h,
                                                   Mv, Dv, Fv, b2 + (size_t)i * Dv, h, 0);
    }

    ln_kernel<<<Mv, blk, 0, stream>>>(h, lnfg, lnfb, y);
    // logits = y @ emb^T  (emb is [V,D] row-major -> BT gemm)
    gemm_kernel<true><<<gV, blk, 0, stream>>>(y, emb, out, Mv, Vv, Dv, nullptr, nullptr, 0);
}

// Round 2
// 5231.563 us; speedup vs baseline: 1.5725x; 1.5725x over previous
//
#include <hip/hip_runtime.h>
#include <math.h>

// Problem constants
#define Bv 2
#define Lv 1024
#define Dv 512
#define Hv 8
#define DH 64
#define Fv 2048
#define NBv 6
#define Vv 32000
#define Mv (Bv*Lv)          // 2048 rows
#define NEGINF -1e10f

typedef __attribute__((ext_vector_type(8))) short short8;   // 8 bf16
typedef __attribute__((ext_vector_type(4))) short short4v;  // 4 bf16
typedef __attribute__((ext_vector_type(4))) float floatx4;
typedef __attribute__((address_space(1))) const void gvoid;
typedef __attribute__((address_space(3))) void svoid;

__device__ __forceinline__ short f2bf(float f) {
    union { float f; unsigned u; } v; v.f = f;
    unsigned r = v.u + 0x7fffu + ((v.u >> 16) & 1u);   // RNE
    return (short)(r >> 16);
}

// ---------------------------------------------------------------------------
// Embedding + sinusoidal positional encoding (fp32 h)
__global__ __launch_bounds__(256)
void embed_kernel(const int* __restrict__ xi, const float* __restrict__ emb,
                  float* __restrict__ h)
{
    const int row = blockIdx.x;
    const int l   = row & (Lv - 1);
    const int tok = xi[row];
    const int tid = threadIdx.x;
#pragma unroll
    for (int s = 0; s < 2; ++s) {
        const int d  = tid + s * 256;
        const int dd = d & 255;
        const float freq = powf(10000.f, (float)dd * (1.f / 256.f));
        const float arg  = (float)l / freq;
        const float pe   = (d < 256) ? sinf(arg) : cosf(arg);
        h[(size_t)row * Dv + d] = emb[(size_t)tok * Dv + d] * 22.62741699796952f + pe;
    }
}

// ---------------------------------------------------------------------------
// fp32 -> bf16 convert (for ctx)
__global__ __launch_bounds__(256)
void cvt_kernel(const float* __restrict__ X, short* __restrict__ Y)
{
    const int i = (blockIdx.x * 256 + threadIdx.x) * 4;
    const float4 v = *(const float4*)(X + i);
    short4v p; p.x = f2bf(v.x); p.y = f2bf(v.y); p.z = f2bf(v.z); p.w = f2bf(v.w);
    *(short4v*)(Y + i) = p;
}

// ---------------------------------------------------------------------------
// LayerNorm: one block per row, 256 threads, D=512; bf16 output
__global__ __launch_bounds__(256)
void ln_kernel(const float* __restrict__ X, const float* __restrict__ g,
               const float* __restrict__ bta, short* __restrict__ Y)
{
    const int row = blockIdx.x, tid = threadIdx.x;
    const float* xr = X + (size_t)row * Dv;
    const float x0 = xr[tid], x1 = xr[tid + 256];
    __shared__ float red[4];

    float s = x0 + x1;
#pragma unroll
    for (int off = 32; off; off >>= 1) s += __shfl_xor(s, off);
    if ((tid & 63) == 0) red[tid >> 6] = s;
    __syncthreads();
    const float mean = (red[0] + red[1] + red[2] + red[3]) * (1.f / Dv);
    __syncthreads();

    const float d0 = x0 - mean, d1 = x1 - mean;
    float v = d0 * d0 + d1 * d1;
#pragma unroll
    for (int off = 32; off; off >>= 1) v += __shfl_xor(v, off);
    if ((tid & 63) == 0) red[tid >> 6] = v;
    __syncthreads();
    const float var  = (red[0] + red[1] + red[2] + red[3]) * (1.f / Dv);
    const float rstd = rsqrtf(var + 1e-6f);

    Y[(size_t)row * Dv + tid]       = f2bf(d0 * rstd * g[tid]       + bta[tid]);
    Y[(size_t)row * Dv + tid + 256] = f2bf(d1 * rstd * g[tid + 256] + bta[tid + 256]);
}

// ---------------------------------------------------------------------------
// bf16 MFMA GEMM. A: bf16 [M,K] rm. B: fp32, BT? [N,K] : [K,N] rm (converted
// to bf16 during LDS staging). C = A@B (+bias) (+residual fp32) (relu?).
// BM=128, BK=32, block 256 = 4 waves (2x2), wave tile 64 x BN/2,
// frags 4 x (BN/32) of 16x16x32.
template <int BN, bool BT, bool OUTBF>
__global__ __launch_bounds__(256)
void mgemm(const short* __restrict__ A, const float* __restrict__ B,
           void* __restrict__ Cp, int M, int N, int K,
           const float* __restrict__ bias,
           const float* __restrict__ residual, int relu)
{
    constexpr int BM = 128, BK = 32;
    constexpr int NF = BN / 32;
    __shared__ short As[BM * BK];
    __shared__ short Bs[BN * BK];
    const int tid  = threadIdx.x;
    const int wave = tid >> 6, lane = tid & 63;
    const int wm = wave & 1, wn = wave >> 1;
    const int quad = lane >> 4, l16 = lane & 15;
    const int m0 = blockIdx.y * BM, n0 = blockIdx.x * BN;

    floatx4 acc[4][NF];
#pragma unroll
    for (int i = 0; i < 4; ++i)
#pragma unroll
        for (int j = 0; j < NF; ++j)
            acc[i][j] = (floatx4){0.f, 0.f, 0.f, 0.f};

    for (int k0 = 0; k0 < K; k0 += BK) {
        __syncthreads();
        // ---- A staging: 2 x 16B per thread via global_load_lds ----
#pragma unroll
        for (int s = 0; s < 2; ++s) {
            const int c = s * 256 + tid;             // chunk = 16B = 8 bf16
            const int row = c >> 2, kp = (c & 3) << 3;
            const short* gp = A + (size_t)(m0 + row) * K + k0 + kp;
            __builtin_amdgcn_global_load_lds((gvoid*)gp, (svoid*)((char*)As + c * 16),
                                             16, 0, 0);
        }
        // ---- B staging: fp32 -> bf16, Bs layout [n][k] ----
        if (!BT) {
            constexpr int QN = BN / 4;               // n-quads
            const int qn = tid % QN, kq = tid / QN;
            if (kq < 8) {
                const float* gp = B + (size_t)(k0 + kq * 4) * N + n0 + qn * 4;
                const float4 r0 = *(const float4*)(gp);
                const float4 r1 = *(const float4*)(gp + N);
                const float4 r2 = *(const float4*)(gp + 2 * (size_t)N);
                const float4 r3 = *(const float4*)(gp + 3 * (size_t)N);
                short4v p;
                p.x = f2bf(r0.x); p.y = f2bf(r1.x); p.z = f2bf(r2.x); p.w = f2bf(r3.x);
                *(short4v*)&Bs[(qn * 4 + 0) * BK + kq * 4] = p;
                p.x = f2bf(r0.y); p.y = f2bf(r1.y); p.z = f2bf(r2.y); p.w = f2bf(r3.y);
                *(short4v*)&Bs[(qn * 4 + 1) * BK + kq * 4] = p;
                p.x = f2bf(r0.z); p.y = f2bf(r1.z); p.z = f2bf(r2.z); p.w = f2bf(r3.z);
                *(short4v*)&Bs[(qn * 4 + 2) * BK + kq * 4] = p;
                p.x = f2bf(r0.w); p.y = f2bf(r1.w); p.z = f2bf(r2.w); p.w = f2bf(r3.w);
                *(short4v*)&Bs[(qn * 4 + 3) * BK + kq * 4] = p;
            }
        } else {
#pragma unroll
            for (int f = 0; f < BN / 32; ++f) {
                const int gidx = f * 256 + tid;      // float4 index
                const int n = gidx >> 3, q = gidx & 7;
                const float4 r = *(const float4*)(B + (size_t)(n0 + n) * K + k0 + q * 4);
                short4v p; p.x = f2bf(r.x); p.y = f2bf(r.y); p.z = f2bf(r.z); p.w = f2bf(r.w);
                *(short4v*)&Bs[n * BK + q * 4] = p;
            }
        }
        __syncthreads();
        // ---- compute: one K=32 MFMA per (mi,ni) ----
        short8 af[4];
#pragma unroll
        for (int mi = 0; mi < 4; ++mi)
            af[mi] = *(short8*)&As[(wm * 64 + mi * 16 + l16) * BK + quad * 8];
#pragma unroll
        for (int ni = 0; ni < NF; ++ni) {
            const short8 bfr = *(short8*)&Bs[(wn * (BN / 2) + ni * 16 + l16) * BK + quad * 8];
#pragma unroll
            for (int mi = 0; mi < 4; ++mi)
                acc[mi][ni] = __builtin_amdgcn_mfma_f32_16x16x32_bf16(af[mi], bfr, acc[mi][ni], 0, 0, 0);
        }
    }

    // ---- epilogue ----
#pragma unroll
    for (int mi = 0; mi < 4; ++mi)
#pragma unroll
        for (int ni = 0; ni < NF; ++ni)
#pragma unroll
            for (int r = 0; r < 4; ++r) {
                const int m = m0 + wm * 64 + mi * 16 + quad * 4 + r;
                const int n = n0 + wn * (BN / 2) + ni * 16 + l16;
                float v = acc[mi][ni][r];
                if (bias)     v += bias[n];
                if (residual) v += residual[(size_t)m * N + n];
                if (relu)     v = fmaxf(v, 0.f);
                if (OUTBF) ((short*)Cp)[(size_t)m * N + n] = f2bf(v);
                else       ((float*)Cp)[(size_t)m * N + n] = v;
            }
}

// ---------------------------------------------------------------------------
// Attention (fp32 in, bf16 out): softmax(Q K^T/8 (+causal)) V.
// grid (L/4, H, B); block 256 = 4 waves; one wave per query row.
__global__ __launch_bounds__(256)
void attn_kernel(const float* __restrict__ Qp, const float* __restrict__ Kp,
                 const float* __restrict__ Vp, short* __restrict__ Op, int causal)
{
    __shared__ float ts[64][65];     // K tile in phase 1, V tile in phase 2
    __shared__ float qs[4][64];
    __shared__ float sc[4][Lv];
    const int tid  = threadIdx.x;
    const int wave = tid >> 6, lane = tid & 63;
    const int hh = blockIdx.y, bb = blockIdx.z;
    const int q  = blockIdx.x * 4 + wave;
    const size_t headoff = (size_t)hh * DH;
    const size_t rowQ = ((size_t)bb * Lv + q) * Dv + headoff;

    qs[wave][lane] = Qp[rowQ + lane] * 0.125f;

    // phase 1: scores
    for (int t = 0; t < 16; ++t) {
        const int j0 = t * 64;
        __syncthreads();
#pragma unroll
        for (int s = 0; s < 16; ++s) {
            const int e = s * 256 + tid;
            const int j = e >> 6, d = e & 63;
            ts[j][d] = Kp[((size_t)bb * Lv + j0 + j) * Dv + headoff + d];
        }
        __syncthreads();
        const int j = j0 + lane;
        float sv;
        if (causal && j > q) {
            sv = NEGINF;
        } else {
            sv = 0.f;
#pragma unroll
            for (int d = 0; d < 64; ++d) sv += qs[wave][d] * ts[lane][d];
        }
        sc[wave][j] = sv;
    }

    // softmax over 1024 scores (wave-local)
    float m = -3.4e38f;
#pragma unroll
    for (int t = 0; t < 16; ++t) m = fmaxf(m, sc[wave][t * 64 + lane]);
#pragma unroll
    for (int off = 32; off; off >>= 1) m = fmaxf(m, __shfl_xor(m, off));
    float sum = 0.f;
#pragma unroll
    for (int t = 0; t < 16; ++t) {
        const float p = expf(sc[wave][t * 64 + lane] - m);
        sc[wave][t * 64 + lane] = p;
        sum += p;
    }
#pragma unroll
    for (int off = 32; off; off >>= 1) sum += __shfl_xor(sum, off);
    const float inv = 1.f / sum;

    // phase 2: P @ V with staged V tiles
    const int jmax = causal ? q : (Lv - 1);
    float o = 0.f;
    for (int t = 0; t < 16; ++t) {
        __syncthreads();
#pragma unroll
        for (int s = 0; s < 16; ++s) {
            const int e = s * 256 + tid;
            const int j = e >> 6, d = e & 63;
            ts[j][d] = Vp[((size_t)bb * Lv + t * 64 + j) * Dv + headoff + d];
        }
        __syncthreads();
        if (t * 64 <= jmax) {
            const int jend = (jmax - t * 64 < 63) ? (jmax - t * 64) : 63;
            for (int jj = 0; jj <= jend; ++jj)
                o += sc[wave][t * 64 + jj] * ts[jj][lane];
        }
    }
    Op[rowQ + lane] = f2bf(o * inv);
}

// ---------------------------------------------------------------------------
extern "C" void kernel_launch(void* const* d_in, const int* in_sizes, int n_in,
                              void* d_out, int out_size, void* d_ws, size_t ws_size,
                              hipStream_t stream)
{
    const int*   x    = (const int*)  d_in[0];
    const float* ctx  = (const float*)d_in[1];
    const float* emb  = (const float*)d_in[2];
    const float* wq_s = (const float*)d_in[3];
    const float* wk_s = (const float*)d_in[4];
    const float* wv_s = (const float*)d_in[5];
    const float* wo_s = (const float*)d_in[6];
    const float* wq_c = (const float*)d_in[7];
    const float* wk_c = (const float*)d_in[8];
    const float* wv_c = (const float*)d_in[9];
    const float* wo_c = (const float*)d_in[10];
    const float* w1   = (const float*)d_in[11];
    const float* b1   = (const float*)d_in[12];
    const float* w2   = (const float*)d_in[13];
    const float* b2   = (const float*)d_in[14];
    const float* ln1g = (const float*)d_in[15];
    const float* ln1b = (const float*)d_in[16];
    const float* ln2g = (const float*)d_in[17];
    const float* ln2b = (const float*)d_in[18];
    const float* ln3g = (const float*)d_in[19];
    const float* ln3b = (const float*)d_in[20];
    const float* lnfg = (const float*)d_in[21];
    const float* lnfb = (const float*)d_in[22];
    float* out = (float*)d_out;

    // workspace layout (22 MB):
    // [0,4M)   h fp32
    // [4,6M)   y bf16
    // [6,8M)   ao bf16
    // [8,10M)  ctx bf16
    // [10,22M) qb/kb/vb fp32 (attention)  -- aliased by ff bf16 [10,18M)
    char* wsb = (char*)d_ws;
    float* h      = (float*)(wsb);
    short* y_bf   = (short*)(wsb + (4u  << 20));
    short* ao_bf  = (short*)(wsb + (6u  << 20));
    short* ctx_bf = (short*)(wsb + (8u  << 20));
    float* qb     = (float*)(wsb + (10u << 20));
    float* kb     = (float*)(wsb + (14u << 20));
    float* vb     = (float*)(wsb + (18u << 20));
    short* ff_bf  = (short*)(wsb + (10u << 20));

    const dim3 blk(256);
    const dim3 gAttn(Lv / 4, Hv, Bv);
    const dim3 gD(Dv / 64, Mv / 128);       // BN=64  : (8,16)
    const dim3 gF(Fv / 128, Mv / 128);      // BN=128 : (16,16)
    const dim3 gV(Vv / 128, Mv / 128);      // BN=128 : (250,16)

    embed_kernel<<<Mv, blk, 0, stream>>>(x, emb, h);
    cvt_kernel<<<(Mv * Dv) / 1024, blk, 0, stream>>>(ctx, ctx_bf);

    for (int i = 0; i < NBv; ++i) {
        const size_t wOff = (size_t)i * Dv * Dv;
        // --- self attention ---
        ln_kernel<<<Mv, blk, 0, stream>>>(h, ln1g + i * Dv, ln1b + i * Dv, y_bf);
        mgemm<64, false, false><<<gD, blk, 0, stream>>>(y_bf, wq_s + wOff, qb, Mv, Dv, Dv, nullptr, nullptr, 0);
        mgemm<64, false, false><<<gD, blk, 0, stream>>>(y_bf, wk_s + wOff, kb, Mv, Dv, Dv, nullptr, nullptr, 0);
        mgemm<64, false, false><<<gD, blk, 0, stream>>>(y_bf, wv_s + wOff, vb, Mv, Dv, Dv, nullptr, nullptr, 0);
        attn_kernel<<<gAttn, blk, 0, stream>>>(qb, kb, vb, ao_bf, 1);
        mgemm<64, false, false><<<gD, blk, 0, stream>>>(ao_bf, wo_s + wOff, h, Mv, Dv, Dv, nullptr, h, 0);
        // --- cross attention ---
        ln_kernel<<<Mv, blk, 0, stream>>>(h, ln2g + i * Dv, ln2b + i * Dv, y_bf);
        mgemm<64, false, false><<<gD, blk, 0, stream>>>(y_bf,   wq_c + wOff, qb, Mv, Dv, Dv, nullptr, nullptr, 0);
        mgemm<64, false, false><<<gD, blk, 0, stream>>>(ctx_bf, wk_c + wOff, kb, Mv, Dv, Dv, nullptr, nullptr, 0);
        mgemm<64, false, false><<<gD, blk, 0, stream>>>(ctx_bf, wv_c + wOff, vb, Mv, Dv, Dv, nullptr, nullptr, 0);
        attn_kernel<<<gAttn, blk, 0, stream>>>(qb, kb, vb, ao_bf, 0);
        mgemm<64, false, false><<<gD, blk, 0, stream>>>(ao_bf, wo_c + wOff, h, Mv, Dv, Dv, nullptr, h, 0);
        // --- feed forward ---
        ln_kernel<<<Mv, blk, 0, stream>>>(h, ln3g + i * Dv, ln3b + i * Dv, y_bf);
        mgemm<128, false, true><<<gF, blk, 0, stream>>>(y_bf, w1 + (size_t)i * Dv * Fv, ff_bf,
                                                        Mv, Fv, Dv, b1 + (size_t)i * Fv, nullptr, 1);
        mgemm<64, false, false><<<gD, blk, 0, stream>>>(ff_bf, w2 + (size_t)i * Fv * Dv, h,
                                                        Mv, Dv, Fv, b2 + (size_t)i * Dv, h, 0);
    }

    ln_kernel<<<Mv, blk, 0, stream>>>(h, lnfg, lnfb, y_bf);
    mgemm<128, true, false><<<gV, blk, 0, stream>>>(y_bf, emb, out, Mv, Vv, Dv, nullptr, nullptr, 0);
}